// Round 4
// baseline (320.530 us; speedup 1.0000x reference)
//
#include <hip/hip_runtime.h>
#include <cstdint>
#include <cstddef>

#define F_ALPHA 0.5f
#define THRESH  0.5f
#define EPS8    1e-8f
#define EPS7    1e-7f
#define MAXM    64
#define CCLS    21
#define GGRP    4      // GTs per bp block
#define LOG2E   1.4426950408889634f
#define LN2     0.6931471805599453f

// ---------------------------------------------------------------------------
// Kernel A: per-GT best prior (bp). One block owns GGRP GTs of one image.
// Register-local running max; ONE cross-lane reduction at the end.
// Also emits per-GT areas (garea). grid = (ceil(M/GGRP), B), block = 256.
// ---------------------------------------------------------------------------
__global__ __launch_bounds__(256)
void bp_kernel(const float4* __restrict__ dbox,
               const float4* __restrict__ gt,
               unsigned* __restrict__ bp,
               float* __restrict__ garea,
               int P, int M)
{
    __shared__ unsigned long long wkey[GGRP][4];

    const int b  = blockIdx.y;
    const int m0 = blockIdx.x * GGRP;
    const int t  = threadIdx.x;
    const int w  = t >> 6, lane = t & 63;

    float4 gb[GGRP]; float ga[GGRP];
    #pragma unroll
    for (int g = 0; g < GGRP; g++) {
        int m = min(m0 + g, M - 1);           // pad entries discarded later
        float4 gg = gt[(size_t)b * M + m];
        gb[g] = gg;
        ga[g] = (gg.z - gg.x) * (gg.w - gg.y);
    }

    float    bestv[GGRP];
    unsigned bestp[GGRP];
    #pragma unroll
    for (int g = 0; g < GGRP; g++) { bestv[g] = 0.f; bestp[g] = 0u; }

    for (int p = t; p < P; p += 256) {
        float4 d = dbox[p];
        float darea = (d.z - d.x) * (d.w - d.y);
        #pragma unroll
        for (int g = 0; g < GGRP; g++) {
            float4 gg = gb[g];
            float lx = fmaxf(d.x, gg.x), ly = fmaxf(d.y, gg.y);
            float rx = fminf(d.z, gg.z), ry = fminf(d.w, gg.w);
            float iw = fmaxf(rx - lx, 0.f), ih = fmaxf(ry - ly, 0.f);
            float inter = iw * ih;
            float iou = inter * __builtin_amdgcn_rcpf(darea + ga[g] - inter);
            // strict > : within-thread ties keep lowest p (p increases)
            if (iou > bestv[g]) { bestv[g] = iou; bestp[g] = (unsigned)p; }
        }
    }

    // one-time reduction: key = iou_bits<<32 | ~p  (max => max iou, min p)
    #pragma unroll
    for (int g = 0; g < GGRP; g++) {
        unsigned long long k =
            ((unsigned long long)__float_as_uint(bestv[g]) << 32)
            | (unsigned long long)(0xFFFFFFFFu - bestp[g]);
        #pragma unroll
        for (int o = 1; o < 64; o <<= 1) {
            unsigned long long k2 = __shfl_xor(k, o, 64);
            if (k2 > k) k = k2;
        }
        if (lane == 0) wkey[g][w] = k;
    }
    __syncthreads();
    if (t < GGRP) {
        unsigned long long k0 = wkey[t][0], k1 = wkey[t][1];
        unsigned long long k2 = wkey[t][2], k3 = wkey[t][3];
        unsigned long long ka = (k0 > k1) ? k0 : k1;
        unsigned long long kb = (k2 > k3) ? k2 : k3;
        unsigned long long k  = (ka > kb) ? ka : kb;
        int m = m0 + t;
        if (m < M) {
            bp[(size_t)b * M + m] = 0xFFFFFFFFu - (unsigned)(k & 0xFFFFFFFFull);
            float4 gg = gt[(size_t)b * M + m];
            garea[(size_t)b * M + m] = (gg.z - gg.x) * (gg.w - gg.y);
        }
        // all-zero row: key stays (0, ~0) -> p = 0, matching argmax fallback
    }
}

// ---------------------------------------------------------------------------
// Kernel B: fused bt (scalar-pipe GT loads) + inverted force-match (LDS
// atomicMax) + focal loss via HW exp2/log2 + GIoU on positives.
// Two-phase 128-row conf staging: LDS 24KB -> 12.2KB => 8 blocks/CU
// (occupancy 4.5 -> 8 waves/SIMD) to hide bt-loop s_load latency.
// ---------------------------------------------------------------------------
__global__ __launch_bounds__(256, 8)
void loss_kernel(const float4* __restrict__ locp,
                 const float*  __restrict__ conf,
                 const float4* __restrict__ dbox,
                 const float4* __restrict__ gt,
                 const float*  __restrict__ garea,
                 const int*    __restrict__ gtl,
                 const unsigned* __restrict__ bp,
                 double* __restrict__ partS,
                 int*    __restrict__ partC,
                 int P, int M)
{
    __shared__ float    scf[128 * CCLS];   // 10752 B two-phase conf tile
    __shared__ int      tl[MAXM];
    __shared__ int      ovr[256];          // force-match override: GT j or -1
    __shared__ double   sv[4];
    __shared__ int      sc[4];

    const int t = threadIdx.x;
    const int b = blockIdx.y;
    const int p0 = blockIdx.x * 256;
    const int p = p0 + t;
    const bool valid = (p < P);

    ovr[t] = -1;
    if (t < M) tl[t] = gtl[(size_t)b * M + t];
    __syncthreads();                       // ovr init visible

    // inverted force-match: last-wins == max GT index wins
    if (t < M) {
        unsigned q = bp[(size_t)b * M + t] - (unsigned)p0;
        if (q < 256u) atomicMax(&ovr[q], t);
    }

    // bt: best GT per prior. GT via wave-uniform scalar loads, uniform CF,
    // zero LDS. Cross-mult compare: iou_m > iou_best <=> inter*bd > bi*den.
    const int pc = valid ? p : (P - 1);
    const float4 d = dbox[pc];
    const float darea = (d.z - d.x) * (d.w - d.y);
    const float4* gtb = gt + (size_t)b * M;
    const float*  gab = garea + (size_t)b * M;
    float bi = -1.0f, bd = 1.0f;           // first compare always true
    int   bm = 0;
    const int Mpad = (M + 3) & ~3;
    for (int m0 = 0; m0 < Mpad; m0 += 4) {
        #pragma unroll
        for (int k = 0; k < 4; k++) {
            int mc = min(m0 + k, M - 1);   // pad = dup of last box: never wins
            float4 g = gtb[mc];
            float ta = gab[mc];
            float lx = fmaxf(d.x, g.x), ly = fmaxf(d.y, g.y);
            float rx = fminf(d.z, g.z), ry = fminf(d.w, g.w);
            float iw = fmaxf(rx - lx, 0.f), ih = fmaxf(ry - ly, 0.f);
            float inter = iw * ih;
            float den = darea + ta - inter;
            if (inter * bd > bi * den) { bi = inter; bd = den; bm = m0 + k; }
        }
    }
    __syncthreads();                       // ovr atomics complete

    int  idx = bm;
    bool pos = (bi >= THRESH * bd);        // iou >= 0.5
    { int j = ovr[t]; if (j >= 0) { idx = j; pos = true; } }
    const int lbl = pos ? tl[idx] : 0;

    const int cnt = min(256, P - p0);
    const float* src = conf + ((size_t)b * P + p0) * CCLS;

    double acc = 0.0;
    int cnt_pos = 0;

    // two-phase focal: stage rows [0,128) then [128,cnt) into the same tile
    #pragma unroll 1
    for (int ph = 0; ph < 2; ph++) {
        const int r0 = ph << 7;
        const int rows = min(128, cnt - r0);      // may be <= 0
        if (rows > 0) {
            const int nf = rows * CCLS;
            const float* s = src + r0 * CCLS;
            if (((uintptr_t)s & 15) == 0) {
                const int n4 = nf >> 2;
                const float4* s4 = (const float4*)s;
                float4* d4 = (float4*)scf;
                for (int i = t; i < n4; i += 256) d4[i] = s4[i];
                for (int i = (n4 << 2) + t; i < nf; i += 256) scf[i] = s[i];
            } else {
                for (int i = t; i < nf; i += 256) scf[i] = s[i];
            }
        }
        __syncthreads();                          // tile ready
        if (valid && (t >> 7) == ph) {
            const int rl = t & 127;
            float xv[CCLS];
            const float* x = scf + rl * CCLS;
            #pragma unroll
            for (int c = 0; c < CCLS; c++) xv[c] = x[c];
            float xl = scf[rl * CCLS + lbl];      // runtime index: direct LDS
            float mx = xv[0];
            #pragma unroll
            for (int c = 1; c < CCLS; c++) mx = fmaxf(mx, xv[c]);
            float sum = 0.f;
            #pragma unroll
            for (int c = 0; c < CCLS; c++)
                sum += __builtin_exp2f((xv[c] - mx) * LOG2E);
            float ce = (mx + __builtin_log2f(sum) * LN2) - xl;
            float pt = __builtin_exp2f(-ce * LOG2E);
            float om = 1.f - pt;
            acc = (double)(F_ALPHA * om * sqrtf(om) * ce);
        }
        __syncthreads();                          // readers done before overwrite
    }

    if (valid && pos) {
        cnt_pos = 1;
        float dw = d.z - d.x, dh = d.w - d.y;
        float dcx = d.x + dw * 0.5f, dcy = d.y + dh * 0.5f;
        float4 g = gt[(size_t)b * M + idx];       // rare divergent gather
        float gw = g.z - g.x, gh = g.w - g.y;
        float gcx = g.x + gw * 0.5f, gcy = g.y + gh * 0.5f;
        float ex = (gcx - dcx) / (dw + EPS8);
        float ey = (gcy - dcy) / (dh + EPS8);
        float ew = logf(gw / (dw + EPS8) + EPS8);
        float eh = logf(gh / (dh + EPS8) + EPS8);
        float tcx = ex * dw + dcx, tcy = ey * dh + dcy;
        float tw = expf(ew) * dw,  th = expf(eh) * dh;
        float t0 = tcx - tw * 0.5f, t1 = tcy - th * 0.5f;
        float t2 = tcx + tw * 0.5f, t3 = tcy + th * 0.5f;
        float4 l = locp[(size_t)b * P + p];
        float pcx = l.x * dw + dcx, pcy = l.y * dh + dcy;
        float pw = expf(l.z) * dw,  ph = expf(l.w) * dh;
        float q0 = pcx - pw * 0.5f, q1 = pcy - ph * 0.5f;
        float q2 = pcx + pw * 0.5f, q3 = pcy + ph * 0.5f;
        float ix0 = fmaxf(q0, t0), iy0 = fmaxf(q1, t1);
        float ix1 = fminf(q2, t2), iy1 = fminf(q3, t3);
        float iw = fmaxf(ix1 - ix0, 0.f), ih = fmaxf(iy1 - iy0, 0.f);
        float inter = iw * ih;
        float pa = (q2 - q0) * (q3 - q1);
        float ta = (t2 - t0) * (t3 - t1);
        float uni = pa + ta - inter;
        float iou = inter / (uni + EPS7);
        float e0 = fminf(q0, t0), e1 = fminf(q1, t1);
        float e2 = fmaxf(q2, t2), e3 = fmaxf(q3, t3);
        float ewd = fmaxf(e2 - e0, 0.f), ehd = fmaxf(e3 - e1, 0.f);
        float encl = ewd * ehd;
        float giou = iou - (encl - uni) / (encl + EPS7);
        acc += (double)(1.f - giou);
    }

    for (int o = 32; o > 0; o >>= 1) {
        acc += __shfl_down(acc, o, 64);
        cnt_pos += __shfl_down(cnt_pos, o, 64);
    }
    int w = t >> 6, lane = t & 63;
    if (lane == 0) { sv[w] = acc; sc[w] = cnt_pos; }
    __syncthreads();
    if (t == 0) {
        int slot = blockIdx.y * gridDim.x + blockIdx.x;
        partS[slot] = sv[0] + sv[1] + sv[2] + sv[3];
        partC[slot] = sc[0] + sc[1] + sc[2] + sc[3];
    }
}

// ---------------------------------------------------------------------------
// Kernel C: reduce per-block partials, divide, write scalar output.
// ---------------------------------------------------------------------------
__global__ __launch_bounds__(256)
void final_kernel(const double* __restrict__ partS,
                  const int*    __restrict__ partC,
                  float* __restrict__ out, int n)
{
    __shared__ double sv[4];
    __shared__ long long sc[4];
    const int t = threadIdx.x;
    double a = 0.0; long long c = 0;
    for (int i = t; i < n; i += 256) { a += partS[i]; c += partC[i]; }
    for (int o = 32; o > 0; o >>= 1) {
        a += __shfl_down(a, o, 64);
        c += __shfl_down(c, o, 64);
    }
    int w = t >> 6, lane = t & 63;
    if (lane == 0) { sv[w] = a; sc[w] = c; }
    __syncthreads();
    if (t == 0) {
        double s = sv[0] + sv[1] + sv[2] + sv[3];
        long long np = sc[0] + sc[1] + sc[2] + sc[3];
        out[0] = (np == 0) ? 0.0f : (float)(s / (double)np);
    }
}

// ---------------------------------------------------------------------------
extern "C" void kernel_launch(void* const* d_in, const int* in_sizes, int n_in,
                              void* d_out, int out_size, void* d_ws, size_t ws_size,
                              hipStream_t stream)
{
    const float* locp = (const float*)d_in[0];   // [B,P,4]
    const float* conf = (const float*)d_in[1];   // [B,P,C]
    const float* dbox = (const float*)d_in[2];   // [P,4]
    const float* gt   = (const float*)d_in[3];   // [B,M,4]
    const int*   gtl  = (const int*)d_in[4];     // [B,M]

    const int P  = in_sizes[2] / 4;
    const long long BP = (long long)in_sizes[0] / 4;
    const int B  = (int)(BP / P);
    const int M  = in_sizes[4] / B;

    const int nblk = (P + 255) / 256;
    const int nPart = nblk * B;

    // ws layout: bp[B*M] u32 | garea[B*M] f32 | partS[nPart] f64 | partC i32
    char* ws = (char*)d_ws;
    unsigned* bp = (unsigned*)ws;
    size_t off = ((size_t)B * M * 4 + 15) & ~(size_t)15;
    float* garea = (float*)(ws + off);
    off += ((size_t)B * M * 4 + 15) & ~(size_t)15;
    double* partS = (double*)(ws + off);
    off += (size_t)nPart * 8;
    int* partC = (int*)(ws + off);

    dim3 gridBP((M + GGRP - 1) / GGRP, B);
    dim3 grid(nblk, B);
    bp_kernel<<<gridBP, 256, 0, stream>>>((const float4*)dbox, (const float4*)gt,
                                          bp, garea, P, M);
    loss_kernel<<<grid, 256, 0, stream>>>((const float4*)locp, conf,
                                          (const float4*)dbox, (const float4*)gt,
                                          garea, gtl, bp, partS, partC, P, M);
    final_kernel<<<1, 256, 0, stream>>>(partS, partC, (float*)d_out, nPart);
}

// Round 6
// 298.460 us; speedup vs baseline: 1.0739x; 1.0739x over previous
//
#include <hip/hip_runtime.h>
#include <cstdint>
#include <cstddef>

#define F_ALPHA 0.5f
#define THRESH  0.5f
#define EPS8    1e-8f
#define EPS7    1e-7f
#define MAXM    64
#define CCLS    21
#define GGRP    4      // GTs per bp block
#define LOG2E   1.4426950408889634f
#define LN2     0.6931471805599453f

// ---------------------------------------------------------------------------
// Kernel A: per-GT best prior (bp). One block owns GGRP GTs of one image.
// Register-local running max; ONE cross-lane reduction at the end.
// Also emits per-GT areas (garea). grid = (ceil(M/GGRP), B), block = 256.
// ---------------------------------------------------------------------------
__global__ __launch_bounds__(256)
void bp_kernel(const float4* __restrict__ dbox,
               const float4* __restrict__ gt,
               unsigned* __restrict__ bp,
               float* __restrict__ garea,
               int P, int M)
{
    __shared__ unsigned long long wkey[GGRP][4];

    const int b  = blockIdx.y;
    const int m0 = blockIdx.x * GGRP;
    const int t  = threadIdx.x;
    const int w  = t >> 6, lane = t & 63;

    float4 gb[GGRP]; float ga[GGRP];
    #pragma unroll
    for (int g = 0; g < GGRP; g++) {
        int m = min(m0 + g, M - 1);           // pad entries discarded later
        float4 gg = gt[(size_t)b * M + m];
        gb[g] = gg;
        ga[g] = (gg.z - gg.x) * (gg.w - gg.y);
    }

    float    bestv[GGRP];
    unsigned bestp[GGRP];
    #pragma unroll
    for (int g = 0; g < GGRP; g++) { bestv[g] = 0.f; bestp[g] = 0u; }

    for (int p = t; p < P; p += 256) {
        float4 d = dbox[p];
        float darea = (d.z - d.x) * (d.w - d.y);
        #pragma unroll
        for (int g = 0; g < GGRP; g++) {
            float4 gg = gb[g];
            float lx = fmaxf(d.x, gg.x), ly = fmaxf(d.y, gg.y);
            float rx = fminf(d.z, gg.z), ry = fminf(d.w, gg.w);
            float iw = fmaxf(rx - lx, 0.f), ih = fmaxf(ry - ly, 0.f);
            float inter = iw * ih;
            float iou = inter * __builtin_amdgcn_rcpf(darea + ga[g] - inter);
            // strict > : within-thread ties keep lowest p (p increases)
            if (iou > bestv[g]) { bestv[g] = iou; bestp[g] = (unsigned)p; }
        }
    }

    // one-time reduction: key = iou_bits<<32 | ~p  (max => max iou, min p)
    #pragma unroll
    for (int g = 0; g < GGRP; g++) {
        unsigned long long k =
            ((unsigned long long)__float_as_uint(bestv[g]) << 32)
            | (unsigned long long)(0xFFFFFFFFu - bestp[g]);
        #pragma unroll
        for (int o = 1; o < 64; o <<= 1) {
            unsigned long long k2 = __shfl_xor(k, o, 64);
            if (k2 > k) k = k2;
        }
        if (lane == 0) wkey[g][w] = k;
    }
    __syncthreads();
    if (t < GGRP) {
        unsigned long long k0 = wkey[t][0], k1 = wkey[t][1];
        unsigned long long k2 = wkey[t][2], k3 = wkey[t][3];
        unsigned long long ka = (k0 > k1) ? k0 : k1;
        unsigned long long kb = (k2 > k3) ? k2 : k3;
        unsigned long long k  = (ka > kb) ? ka : kb;
        int m = m0 + t;
        if (m < M) {
            bp[(size_t)b * M + m] = 0xFFFFFFFFu - (unsigned)(k & 0xFFFFFFFFull);
            float4 gg = gt[(size_t)b * M + m];
            garea[(size_t)b * M + m] = (gg.z - gg.x) * (gg.w - gg.y);
        }
        // all-zero row: key stays (0, ~0) -> p = 0, matching argmax fallback
    }
}

// ---------------------------------------------------------------------------
// Kernel B: fused bt (per-prior best GT via SCALAR-pipe GT loads) + inverted
// force-match (LDS atomicMax) + focal loss via HW exp2/log2 + GIoU on
// positives. Structure = R3 (best measured VALU utilization, 84%); only
// instruction-count cuts applied (kernel is VALU-issue-bound: busy-time
// ~74us constant across R2-R4 while duration varied with utilization).
// ---------------------------------------------------------------------------
__global__ __launch_bounds__(256, 6)
void loss_kernel(const float4* __restrict__ locp,
                 const float*  __restrict__ conf,
                 const float4* __restrict__ dbox,
                 const float4* __restrict__ gt,
                 const float*  __restrict__ garea,
                 const int*    __restrict__ gtl,
                 const unsigned* __restrict__ bp,
                 double* __restrict__ partS,
                 int*    __restrict__ partC,
                 int P, int M)
{
    __shared__ float    scf[256 * CCLS];   // 21504 B conf tile
    __shared__ float4   tb[MAXM];          // GT boxes (divergent idx gather only)
    __shared__ int      tl[MAXM];
    __shared__ int      ovr[256];          // force-match override: GT j or -1
    __shared__ double   sv[4];
    __shared__ int      sc[4];

    const int t = threadIdx.x;
    const int b = blockIdx.y;
    const int p0 = blockIdx.x * 256;
    const int p = p0 + t;
    const bool valid = (p < P);

    ovr[t] = -1;
    if (t < M) {
        tb[t] = gt[(size_t)b * M + t];
        tl[t] = gtl[(size_t)b * M + t];
    }

    // stage conf tile: contiguous [cnt*21] floats, coalesced float4
    const int cnt = min(256, P - p0);
    const int nf = cnt * CCLS;
    const float* src = conf + ((size_t)b * P + p0) * CCLS;
    {
        const int n4 = nf >> 2;
        const float4* s4 = (const float4*)src;
        float4* d4 = (float4*)scf;
        for (int i = t; i < n4; i += 256) d4[i] = s4[i];
        for (int i = (n4 << 2) + t; i < nf; i += 256) scf[i] = src[i];
    }
    __syncthreads();

    // inverted force-match: last-wins == max GT index wins
    if (t < M) {
        unsigned q = bp[(size_t)b * M + t] - (unsigned)p0;
        if (q < 256u) atomicMax(&ovr[q], t);
    }

    // bt: best GT per prior. GT data arrives via wave-uniform (scalar) loads,
    // uniform control flow, zero LDS in this loop. Cross-mult compare:
    // iou_m > iou_best  <=>  inter_m*bd > bi*den_m   (dens always > 0)
    float4 d = make_float4(0.f, 0.f, 0.f, 0.f);
    float bi = -1.0f, bd = 1.0f;   // first compare always true at m=0
    int   bm = 0;
    if (valid) {
        d = dbox[p];
        const float darea = (d.z - d.x) * (d.w - d.y);
        const float4* gtb = gt + (size_t)b * M;
        const float*  gab = garea + (size_t)b * M;
        #pragma unroll 4
        for (int m = 0; m < M; m++) {
            float4 g = gtb[m];
            float ta = gab[m];
            float lx = fmaxf(d.x, g.x), ly = fmaxf(d.y, g.y);
            float rx = fminf(d.z, g.z), ry = fminf(d.w, g.w);
            float iw = fmaxf(rx - lx, 0.f), ih = fmaxf(ry - ly, 0.f);
            float inter = iw * ih;
            float den = darea + ta - inter;
            if (inter * bd > bi * den) { bi = inter; bd = den; bm = m; }
        }
    }
    __syncthreads();   // ovr table complete

    double acc = 0.0;
    int cnt_pos = 0;
    if (valid) {
        int  idx = bm;
        bool pos = (bi >= THRESH * bd);        // iou >= 0.5
        { int j = ovr[t]; if (j >= 0) { idx = j; pos = true; } }
        int lbl = pos ? tl[idx] : 0;

        // focal loss: scf -> registers ONCE (static indexing only); HW exp2
        float xv[CCLS];
        const float* x = scf + t * CCLS;
        #pragma unroll
        for (int c = 0; c < CCLS; c++) xv[c] = x[c];
        float xl = scf[t * CCLS + lbl];        // runtime index: direct LDS
        float mx = xv[0];
        #pragma unroll
        for (int c = 1; c < CCLS; c++) mx = fmaxf(mx, xv[c]);
        float h = mx * LOG2E;
        float sum = 0.f;
        #pragma unroll
        for (int c = 0; c < CCLS; c++)
            sum += __builtin_exp2f(__builtin_fmaf(xv[c], LOG2E, -h));
        float ce = (mx + __builtin_log2f(sum) * LN2) - xl;
        float pt = __builtin_exp2f(-ce * LOG2E);
        float om = 1.f - pt;
        acc = (double)(F_ALPHA * om * __builtin_sqrtf(om) * ce);

        if (pos) {
            cnt_pos = 1;
            float dw = d.z - d.x, dh = d.w - d.y;
            float dcx = d.x + dw * 0.5f, dcy = d.y + dh * 0.5f;
            float4 g = tb[idx];
            float gw = g.z - g.x, gh = g.w - g.y;
            float gcx = g.x + gw * 0.5f, gcy = g.y + gh * 0.5f;
            float ex = (gcx - dcx) / (dw + EPS8);
            float ey = (gcy - dcy) / (dh + EPS8);
            float ew = logf(gw / (dw + EPS8) + EPS8);
            float eh = logf(gh / (dh + EPS8) + EPS8);
            float tcx = ex * dw + dcx, tcy = ey * dh + dcy;
            float tw = expf(ew) * dw,  th = expf(eh) * dh;
            float t0 = tcx - tw * 0.5f, t1 = tcy - th * 0.5f;
            float t2 = tcx + tw * 0.5f, t3 = tcy + th * 0.5f;
            float4 l = locp[(size_t)b * P + p];
            float pcx = l.x * dw + dcx, pcy = l.y * dh + dcy;
            float pw = expf(l.z) * dw,  ph = expf(l.w) * dh;
            float q0 = pcx - pw * 0.5f, q1 = pcy - ph * 0.5f;
            float q2 = pcx + pw * 0.5f, q3 = pcy + ph * 0.5f;
            float ix0 = fmaxf(q0, t0), iy0 = fmaxf(q1, t1);
            float ix1 = fminf(q2, t2), iy1 = fminf(q3, t3);
            float iw = fmaxf(ix1 - ix0, 0.f), ih = fmaxf(iy1 - iy0, 0.f);
            float inter = iw * ih;
            float pa = (q2 - q0) * (q3 - q1);
            float ta = (t2 - t0) * (t3 - t1);
            float uni = pa + ta - inter;
            float iou = inter / (uni + EPS7);
            float e0 = fminf(q0, t0), e1 = fminf(q1, t1);
            float e2 = fmaxf(q2, t2), e3 = fmaxf(q3, t3);
            float ewd = fmaxf(e2 - e0, 0.f), ehd = fmaxf(e3 - e1, 0.f);
            float encl = ewd * ehd;
            float giou = iou - (encl - uni) / (encl + EPS7);
            acc += (double)(1.f - giou);
        }
    }

    for (int o = 32; o > 0; o >>= 1) {
        acc += __shfl_down(acc, o, 64);
        cnt_pos += __shfl_down(cnt_pos, o, 64);
    }
    int w = t >> 6, lane = t & 63;
    if (lane == 0) { sv[w] = acc; sc[w] = cnt_pos; }
    __syncthreads();
    if (t == 0) {
        int slot = blockIdx.y * gridDim.x + blockIdx.x;
        partS[slot] = sv[0] + sv[1] + sv[2] + sv[3];
        partC[slot] = sc[0] + sc[1] + sc[2] + sc[3];
    }
}

// ---------------------------------------------------------------------------
// Kernel C: reduce per-block partials, divide, write scalar output.
// ---------------------------------------------------------------------------
__global__ __launch_bounds__(256)
void final_kernel(const double* __restrict__ partS,
                  const int*    __restrict__ partC,
                  float* __restrict__ out, int n)
{
    __shared__ double sv[4];
    __shared__ long long sc[4];
    const int t = threadIdx.x;
    double a = 0.0; long long c = 0;
    for (int i = t; i < n; i += 256) { a += partS[i]; c += partC[i]; }
    for (int o = 32; o > 0; o >>= 1) {
        a += __shfl_down(a, o, 64);
        c += __shfl_down(c, o, 64);
    }
    int w = t >> 6, lane = t & 63;
    if (lane == 0) { sv[w] = a; sc[w] = c; }
    __syncthreads();
    if (t == 0) {
        double s = sv[0] + sv[1] + sv[2] + sv[3];
        long long np = sc[0] + sc[1] + sc[2] + sc[3];
        out[0] = (np == 0) ? 0.0f : (float)(s / (double)np);
    }
}

// ---------------------------------------------------------------------------
extern "C" void kernel_launch(void* const* d_in, const int* in_sizes, int n_in,
                              void* d_out, int out_size, void* d_ws, size_t ws_size,
                              hipStream_t stream)
{
    const float* locp = (const float*)d_in[0];   // [B,P,4]
    const float* conf = (const float*)d_in[1];   // [B,P,C]
    const float* dbox = (const float*)d_in[2];   // [P,4]
    const float* gt   = (const float*)d_in[3];   // [B,M,4]
    const int*   gtl  = (const int*)d_in[4];     // [B,M]

    const int P  = in_sizes[2] / 4;
    const long long BP = (long long)in_sizes[0] / 4;
    const int B  = (int)(BP / P);
    const int M  = in_sizes[4] / B;

    const int nblk = (P + 255) / 256;
    const int nPart = nblk * B;

    // ws layout: bp[B*M] u32 | garea[B*M] f32 | partS[nPart] f64 | partC i32
    char* ws = (char*)d_ws;
    unsigned* bp = (unsigned*)ws;
    size_t off = ((size_t)B * M * 4 + 15) & ~(size_t)15;
    float* garea = (float*)(ws + off);
    off += ((size_t)B * M * 4 + 15) & ~(size_t)15;
    double* partS = (double*)(ws + off);
    off += (size_t)nPart * 8;
    int* partC = (int*)(ws + off);

    dim3 gridBP((M + GGRP - 1) / GGRP, B);
    dim3 grid(nblk, B);
    bp_kernel<<<gridBP, 256, 0, stream>>>((const float4*)dbox, (const float4*)gt,
                                          bp, garea, P, M);
    loss_kernel<<<grid, 256, 0, stream>>>((const float4*)locp, conf,
                                          (const float4*)dbox, (const float4*)gt,
                                          garea, gtl, bp, partS, partC, P, M);
    final_kernel<<<1, 256, 0, stream>>>(partS, partC, (float*)d_out, nPart);
}

// Round 7
// 294.779 us; speedup vs baseline: 1.0874x; 1.0125x over previous
//
#include <hip/hip_runtime.h>
#include <cstdint>
#include <cstddef>

#define F_ALPHA 0.5f
#define THRESH  0.5f
#define EPS8    1e-8f
#define EPS7    1e-7f
#define MAXM    64
#define CCLS    21
#define GGRP    4      // GTs per bp block
#define LOG2E   1.4426950408889634f
#define LN2     0.6931471805599453f

// unaligned 16B global load (conf rows are 84B-strided, only 4B-aligned)
__device__ __forceinline__ float4 ldg4u(const float* p) {
    float4 v;
    __builtin_memcpy(&v, p, 16);
    return v;
}

// ---------------------------------------------------------------------------
// Kernel A: per-GT best prior (bp). One block owns GGRP GTs of one image.
// Register-local running max; ONE cross-lane reduction at the end.
// Also emits per-GT areas (garea). grid = (ceil(M/GGRP), B), block = 256.
// ---------------------------------------------------------------------------
__global__ __launch_bounds__(256)
void bp_kernel(const float4* __restrict__ dbox,
               const float4* __restrict__ gt,
               unsigned* __restrict__ bp,
               float* __restrict__ garea,
               int P, int M)
{
    __shared__ unsigned long long wkey[GGRP][4];

    const int b  = blockIdx.y;
    const int m0 = blockIdx.x * GGRP;
    const int t  = threadIdx.x;
    const int w  = t >> 6, lane = t & 63;

    float4 gb[GGRP]; float ga[GGRP];
    #pragma unroll
    for (int g = 0; g < GGRP; g++) {
        int m = min(m0 + g, M - 1);           // pad entries discarded later
        float4 gg = gt[(size_t)b * M + m];
        gb[g] = gg;
        ga[g] = (gg.z - gg.x) * (gg.w - gg.y);
    }

    float    bestv[GGRP];
    unsigned bestp[GGRP];
    #pragma unroll
    for (int g = 0; g < GGRP; g++) { bestv[g] = 0.f; bestp[g] = 0u; }

    for (int p = t; p < P; p += 256) {
        float4 d = dbox[p];
        float darea = (d.z - d.x) * (d.w - d.y);
        #pragma unroll
        for (int g = 0; g < GGRP; g++) {
            float4 gg = gb[g];
            float lx = fmaxf(d.x, gg.x), ly = fmaxf(d.y, gg.y);
            float rx = fminf(d.z, gg.z), ry = fminf(d.w, gg.w);
            float iw = fmaxf(rx - lx, 0.f), ih = fmaxf(ry - ly, 0.f);
            float inter = iw * ih;
            float iou = inter * __builtin_amdgcn_rcpf(darea + ga[g] - inter);
            // strict > : within-thread ties keep lowest p (p increases)
            if (iou > bestv[g]) { bestv[g] = iou; bestp[g] = (unsigned)p; }
        }
    }

    // one-time reduction: key = iou_bits<<32 | ~p  (max => max iou, min p)
    #pragma unroll
    for (int g = 0; g < GGRP; g++) {
        unsigned long long k =
            ((unsigned long long)__float_as_uint(bestv[g]) << 32)
            | (unsigned long long)(0xFFFFFFFFu - bestp[g]);
        #pragma unroll
        for (int o = 1; o < 64; o <<= 1) {
            unsigned long long k2 = __shfl_xor(k, o, 64);
            if (k2 > k) k = k2;
        }
        if (lane == 0) wkey[g][w] = k;
    }
    __syncthreads();
    if (t < GGRP) {
        unsigned long long k0 = wkey[t][0], k1 = wkey[t][1];
        unsigned long long k2 = wkey[t][2], k3 = wkey[t][3];
        unsigned long long ka = (k0 > k1) ? k0 : k1;
        unsigned long long kb = (k2 > k3) ? k2 : k3;
        unsigned long long k  = (ka > kb) ? ka : kb;
        int m = m0 + t;
        if (m < M) {
            bp[(size_t)b * M + m] = 0xFFFFFFFFu - (unsigned)(k & 0xFFFFFFFFull);
            float4 gg = gt[(size_t)b * M + m];
            garea[(size_t)b * M + m] = (gg.z - gg.x) * (gg.w - gg.y);
        }
        // all-zero row: key stays (0, ~0) -> p = 0, matching argmax fallback
    }
}

// ---------------------------------------------------------------------------
// per-anchor loss: focal (direct global conf loads) + GIoU on positives.
// All transcendentals via HW exp2/log2/rcp (fast, <=1ulp; feeds a tolerance-
// checked scalar output).
// ---------------------------------------------------------------------------
__device__ __forceinline__ void anchor_loss(
    bool valid, float4 d, float bi, float bd, int bm, int ov,
    const int* __restrict__ tl, const float4* __restrict__ tb,
    const float* confRow, const float4* locpP,
    double& acc, int& cnt_pos)
{
    if (!valid) return;

    int  idx = bm;
    bool pos = (bi >= THRESH * bd);        // iou >= 0.5
    if (ov >= 0) { idx = ov; pos = true; }
    const int lbl = pos ? tl[idx] : 0;

    // focal: 21 contiguous floats, direct global (5x dwordx4-unaligned + 1)
    float xv[CCLS];
    float4 v0 = ldg4u(confRow +  0);
    float4 v1 = ldg4u(confRow +  4);
    float4 v2 = ldg4u(confRow +  8);
    float4 v3 = ldg4u(confRow + 12);
    float4 v4 = ldg4u(confRow + 16);
    xv[0]=v0.x;  xv[1]=v0.y;  xv[2]=v0.z;  xv[3]=v0.w;
    xv[4]=v1.x;  xv[5]=v1.y;  xv[6]=v1.z;  xv[7]=v1.w;
    xv[8]=v2.x;  xv[9]=v2.y;  xv[10]=v2.z; xv[11]=v2.w;
    xv[12]=v3.x; xv[13]=v3.y; xv[14]=v3.z; xv[15]=v3.w;
    xv[16]=v4.x; xv[17]=v4.y; xv[18]=v4.z; xv[19]=v4.w;
    xv[20]=confRow[20];
    float xl = confRow[lbl];               // L1-hot 4B re-read

    float mx = xv[0];
    #pragma unroll
    for (int c = 1; c < CCLS; c++) mx = fmaxf(mx, xv[c]);
    float h = mx * LOG2E;
    float sum = 0.f;
    #pragma unroll
    for (int c = 0; c < CCLS; c++)
        sum += __builtin_exp2f(__builtin_fmaf(xv[c], LOG2E, -h));
    float ce = (mx + __builtin_log2f(sum) * LN2) - xl;
    float pt = __builtin_exp2f(-ce * LOG2E);
    float om = 1.f - pt;
    acc += (double)(F_ALPHA * om * __builtin_sqrtf(om) * ce);

    if (pos) {
        cnt_pos += 1;
        float dw = d.z - d.x, dh = d.w - d.y;
        float dcx = d.x + dw * 0.5f, dcy = d.y + dh * 0.5f;
        float4 g = tb[idx];
        float gw = g.z - g.x, gh = g.w - g.y;
        float gcx = g.x + gw * 0.5f, gcy = g.y + gh * 0.5f;
        float rdw = __builtin_amdgcn_rcpf(dw + EPS8);
        float rdh = __builtin_amdgcn_rcpf(dh + EPS8);
        float ex = (gcx - dcx) * rdw;
        float ey = (gcy - dcy) * rdh;
        float ew = __builtin_log2f(gw * rdw + EPS8) * LN2;
        float eh = __builtin_log2f(gh * rdh + EPS8) * LN2;
        float tcx = ex * dw + dcx, tcy = ey * dh + dcy;
        float tw = __builtin_exp2f(ew * LOG2E) * dw;
        float th = __builtin_exp2f(eh * LOG2E) * dh;
        float t0 = tcx - tw * 0.5f, t1 = tcy - th * 0.5f;
        float t2 = tcx + tw * 0.5f, t3 = tcy + th * 0.5f;
        float4 l = *locpP;
        float pcx = l.x * dw + dcx, pcy = l.y * dh + dcy;
        float pw = __builtin_exp2f(l.z * LOG2E) * dw;
        float ph = __builtin_exp2f(l.w * LOG2E) * dh;
        float q0 = pcx - pw * 0.5f, q1 = pcy - ph * 0.5f;
        float q2 = pcx + pw * 0.5f, q3 = pcy + ph * 0.5f;
        float ix0 = fmaxf(q0, t0), iy0 = fmaxf(q1, t1);
        float ix1 = fminf(q2, t2), iy1 = fminf(q3, t3);
        float iw = fmaxf(ix1 - ix0, 0.f), ih = fmaxf(iy1 - iy0, 0.f);
        float inter = iw * ih;
        float pa = (q2 - q0) * (q3 - q1);
        float ta = (t2 - t0) * (t3 - t1);
        float uni = pa + ta - inter;
        float iou = inter * __builtin_amdgcn_rcpf(uni + EPS7);
        float e0 = fminf(q0, t0), e1 = fminf(q1, t1);
        float e2 = fmaxf(q2, t2), e3 = fmaxf(q3, t3);
        float ewd = fmaxf(e2 - e0, 0.f), ehd = fmaxf(e3 - e1, 0.f);
        float encl = ewd * ehd;
        float giou = iou - (encl - uni) * __builtin_amdgcn_rcpf(encl + EPS7);
        acc += (double)(1.f - giou);
    }
}

// ---------------------------------------------------------------------------
// Kernel B: fused bt + inverted force-match + focal + GIoU.
// 2 anchors per thread (block covers 512 priors): halves wave count and all
// per-wave fixed costs (GT s_load stream, f64 reduction, barriers), doubles
// bt-loop ILP. No conf LDS staging: direct global loads (contiguous 84B/row
// consumes full lines wave-wide). LDS: ~3.6 KB.
// ---------------------------------------------------------------------------
__global__ __launch_bounds__(256, 4)
void loss_kernel(const float4* __restrict__ locp,
                 const float*  __restrict__ conf,
                 const float4* __restrict__ dbox,
                 const float4* __restrict__ gt,
                 const float*  __restrict__ garea,
                 const int*    __restrict__ gtl,
                 const unsigned* __restrict__ bp,
                 double* __restrict__ partS,
                 int*    __restrict__ partC,
                 int P, int M)
{
    __shared__ float4 tb[MAXM];
    __shared__ int    tl[MAXM];
    __shared__ int    ovr[512];            // force-match override: GT j or -1
    __shared__ double sv[4];
    __shared__ int    sc[4];

    const int t  = threadIdx.x;
    const int b  = blockIdx.y;
    const int p0 = blockIdx.x * 512;
    const int pA = p0 + t;
    const int pB = p0 + 256 + t;
    const bool validA = (pA < P);
    const bool validB = (pB < P);

    ovr[t] = -1; ovr[t + 256] = -1;
    if (t < M) {
        tb[t] = gt[(size_t)b * M + t];
        tl[t] = gtl[(size_t)b * M + t];
    }
    __syncthreads();                       // ovr/tb/tl init visible

    // inverted force-match: last-wins == max GT index wins
    if (t < M) {
        unsigned q = bp[(size_t)b * M + t] - (unsigned)p0;
        if (q < 512u) atomicMax(&ovr[q], t);
    }

    // bt for both anchors; GT via wave-uniform scalar loads, zero LDS.
    // Cross-mult compare: iou_m > iou_best <=> inter_m*bd > bi*den_m.
    const float4 dA = dbox[validA ? pA : (P - 1)];
    const float4 dB = dbox[validB ? pB : (P - 1)];
    const float daA = (dA.z - dA.x) * (dA.w - dA.y);
    const float daB = (dB.z - dB.x) * (dB.w - dB.y);
    const float4* gtb = gt + (size_t)b * M;
    const float*  gab = garea + (size_t)b * M;
    float biA = -1.f, bdA = 1.f, biB = -1.f, bdB = 1.f;
    int   bmA = 0, bmB = 0;
    #pragma unroll 2
    for (int m = 0; m < M; m++) {
        float4 g = gtb[m];
        float ta = gab[m];
        {
            float lx = fmaxf(dA.x, g.x), ly = fmaxf(dA.y, g.y);
            float rx = fminf(dA.z, g.z), ry = fminf(dA.w, g.w);
            float iw = fmaxf(rx - lx, 0.f), ih = fmaxf(ry - ly, 0.f);
            float inter = iw * ih;
            float den = daA + ta - inter;
            if (inter * bdA > biA * den) { biA = inter; bdA = den; bmA = m; }
        }
        {
            float lx = fmaxf(dB.x, g.x), ly = fmaxf(dB.y, g.y);
            float rx = fminf(dB.z, g.z), ry = fminf(dB.w, g.w);
            float iw = fmaxf(rx - lx, 0.f), ih = fmaxf(ry - ly, 0.f);
            float inter = iw * ih;
            float den = daB + ta - inter;
            if (inter * bdB > biB * den) { biB = inter; bdB = den; bmB = m; }
        }
    }
    __syncthreads();                       // ovr atomics complete

    double acc = 0.0;
    int cnt_pos = 0;
    const size_t bP = (size_t)b * P;
    anchor_loss(validA, dA, biA, bdA, bmA, ovr[t], tl, tb,
                conf + (bP + pA) * CCLS, locp + bP + pA, acc, cnt_pos);
    anchor_loss(validB, dB, biB, bdB, bmB, ovr[t + 256], tl, tb,
                conf + (bP + (validB ? pB : 0)) * CCLS,
                locp + bP + (validB ? pB : 0), acc, cnt_pos);

    for (int o = 32; o > 0; o >>= 1) {
        acc += __shfl_down(acc, o, 64);
        cnt_pos += __shfl_down(cnt_pos, o, 64);
    }
    int w = t >> 6, lane = t & 63;
    if (lane == 0) { sv[w] = acc; sc[w] = cnt_pos; }
    __syncthreads();
    if (t == 0) {
        int slot = blockIdx.y * gridDim.x + blockIdx.x;
        partS[slot] = sv[0] + sv[1] + sv[2] + sv[3];
        partC[slot] = sc[0] + sc[1] + sc[2] + sc[3];
    }
}

// ---------------------------------------------------------------------------
// Kernel C: reduce per-block partials, divide, write scalar output.
// ---------------------------------------------------------------------------
__global__ __launch_bounds__(256)
void final_kernel(const double* __restrict__ partS,
                  const int*    __restrict__ partC,
                  float* __restrict__ out, int n)
{
    __shared__ double sv[4];
    __shared__ long long sc[4];
    const int t = threadIdx.x;
    double a = 0.0; long long c = 0;
    for (int i = t; i < n; i += 256) { a += partS[i]; c += partC[i]; }
    for (int o = 32; o > 0; o >>= 1) {
        a += __shfl_down(a, o, 64);
        c += __shfl_down(c, o, 64);
    }
    int w = t >> 6, lane = t & 63;
    if (lane == 0) { sv[w] = a; sc[w] = c; }
    __syncthreads();
    if (t == 0) {
        double s = sv[0] + sv[1] + sv[2] + sv[3];
        long long np = sc[0] + sc[1] + sc[2] + sc[3];
        out[0] = (np == 0) ? 0.0f : (float)(s / (double)np);
    }
}

// ---------------------------------------------------------------------------
extern "C" void kernel_launch(void* const* d_in, const int* in_sizes, int n_in,
                              void* d_out, int out_size, void* d_ws, size_t ws_size,
                              hipStream_t stream)
{
    const float* locp = (const float*)d_in[0];   // [B,P,4]
    const float* conf = (const float*)d_in[1];   // [B,P,C]
    const float* dbox = (const float*)d_in[2];   // [P,4]
    const float* gt   = (const float*)d_in[3];   // [B,M,4]
    const int*   gtl  = (const int*)d_in[4];     // [B,M]

    const int P  = in_sizes[2] / 4;
    const long long BP = (long long)in_sizes[0] / 4;
    const int B  = (int)(BP / P);
    const int M  = in_sizes[4] / B;

    const int nblk = (P + 511) / 512;
    const int nPart = nblk * B;

    // ws layout: bp[B*M] u32 | garea[B*M] f32 | partS[nPart] f64 | partC i32
    char* ws = (char*)d_ws;
    unsigned* bp = (unsigned*)ws;
    size_t off = ((size_t)B * M * 4 + 15) & ~(size_t)15;
    float* garea = (float*)(ws + off);
    off += ((size_t)B * M * 4 + 15) & ~(size_t)15;
    double* partS = (double*)(ws + off);
    off += (size_t)nPart * 8;
    int* partC = (int*)(ws + off);

    dim3 gridBP((M + GGRP - 1) / GGRP, B);
    dim3 grid(nblk, B);
    bp_kernel<<<gridBP, 256, 0, stream>>>((const float4*)dbox, (const float4*)gt,
                                          bp, garea, P, M);
    loss_kernel<<<grid, 256, 0, stream>>>((const float4*)locp, conf,
                                          (const float4*)dbox, (const float4*)gt,
                                          garea, gtl, bp, partS, partC, P, M);
    final_kernel<<<1, 256, 0, stream>>>(partS, partC, (float*)d_out, nPart);
}

// Round 8
// 285.702 us; speedup vs baseline: 1.1219x; 1.0318x over previous
//
#include <hip/hip_runtime.h>
#include <cstdint>
#include <cstddef>

#define F_ALPHA 0.5f
#define THRESH  0.5f
#define EPS8    1e-8f
#define EPS7    1e-7f
#define MAXM    64
#define CCLS    21
#define GGRP    4      // GTs per bp block
#define LOG2E   1.4426950408889634f
#define LN2     0.6931471805599453f

// unaligned 16B global load (conf rows are 84B-strided, only 4B-aligned)
__device__ __forceinline__ float4 ldg4u(const float* p) {
    float4 v;
    __builtin_memcpy(&v, p, 16);
    return v;
}

// ---------------------------------------------------------------------------
// Kernel A: per-GT best prior (bp). One block owns GGRP GTs of one image.
// Register-local running max; ONE cross-lane reduction at the end.
// Also emits per-GT areas (garea). grid = (ceil(M/GGRP), B), block = 256.
// ---------------------------------------------------------------------------
__global__ __launch_bounds__(256)
void bp_kernel(const float4* __restrict__ dbox,
               const float4* __restrict__ gt,
               unsigned* __restrict__ bp,
               float* __restrict__ garea,
               int P, int M)
{
    __shared__ unsigned long long wkey[GGRP][4];

    const int b  = blockIdx.y;
    const int m0 = blockIdx.x * GGRP;
    const int t  = threadIdx.x;
    const int w  = t >> 6, lane = t & 63;

    float4 gb[GGRP]; float ga[GGRP];
    #pragma unroll
    for (int g = 0; g < GGRP; g++) {
        int m = min(m0 + g, M - 1);           // pad entries discarded later
        float4 gg = gt[(size_t)b * M + m];
        gb[g] = gg;
        ga[g] = (gg.z - gg.x) * (gg.w - gg.y);
    }

    float    bestv[GGRP];
    unsigned bestp[GGRP];
    #pragma unroll
    for (int g = 0; g < GGRP; g++) { bestv[g] = 0.f; bestp[g] = 0u; }

    for (int p = t; p < P; p += 256) {
        float4 d = dbox[p];
        float darea = (d.z - d.x) * (d.w - d.y);
        #pragma unroll
        for (int g = 0; g < GGRP; g++) {
            float4 gg = gb[g];
            float lx = fmaxf(d.x, gg.x), ly = fmaxf(d.y, gg.y);
            float rx = fminf(d.z, gg.z), ry = fminf(d.w, gg.w);
            float iw = fmaxf(rx - lx, 0.f), ih = fmaxf(ry - ly, 0.f);
            float inter = iw * ih;
            float iou = inter * __builtin_amdgcn_rcpf(darea + ga[g] - inter);
            // strict > : within-thread ties keep lowest p (p increases)
            if (iou > bestv[g]) { bestv[g] = iou; bestp[g] = (unsigned)p; }
        }
    }

    // one-time reduction: key = iou_bits<<32 | ~p  (max => max iou, min p)
    #pragma unroll
    for (int g = 0; g < GGRP; g++) {
        unsigned long long k =
            ((unsigned long long)__float_as_uint(bestv[g]) << 32)
            | (unsigned long long)(0xFFFFFFFFu - bestp[g]);
        #pragma unroll
        for (int o = 1; o < 64; o <<= 1) {
            unsigned long long k2 = __shfl_xor(k, o, 64);
            if (k2 > k) k = k2;
        }
        if (lane == 0) wkey[g][w] = k;
    }
    __syncthreads();
    if (t < GGRP) {
        unsigned long long k0 = wkey[t][0], k1 = wkey[t][1];
        unsigned long long k2 = wkey[t][2], k3 = wkey[t][3];
        unsigned long long ka = (k0 > k1) ? k0 : k1;
        unsigned long long kb = (k2 > k3) ? k2 : k3;
        unsigned long long k  = (ka > kb) ? ka : kb;
        int m = m0 + t;
        if (m < M) {
            bp[(size_t)b * M + m] = 0xFFFFFFFFu - (unsigned)(k & 0xFFFFFFFFull);
            float4 gg = gt[(size_t)b * M + m];
            garea[(size_t)b * M + m] = (gg.z - gg.x) * (gg.w - gg.y);
        }
        // all-zero row: key stays (0, ~0) -> p = 0, matching argmax fallback
    }
}

// ---------------------------------------------------------------------------
// focal + GIoU for one anchor, conf row already in registers (v0..v4,x20
// loaded BEFORE the bt loop -> latency hidden under ~3400cyc of bt compute).
// ---------------------------------------------------------------------------
__device__ __forceinline__ void anchor_loss(
    bool valid, float4 d, float bi, float bd, int bm, int ov,
    const int* __restrict__ tl, const float4* __restrict__ tb,
    float4 v0, float4 v1, float4 v2, float4 v3, float4 v4, float x20,
    const float* confRow, const float4* locpP,
    double& acc, int& cnt_pos)
{
    if (!valid) return;

    int  idx = bm;
    bool pos = (bi >= THRESH * bd);        // iou >= 0.5
    if (ov >= 0) { idx = ov; pos = true; }
    const int lbl = pos ? tl[idx] : 0;

    float xv[CCLS];
    xv[0]=v0.x;  xv[1]=v0.y;  xv[2]=v0.z;  xv[3]=v0.w;
    xv[4]=v1.x;  xv[5]=v1.y;  xv[6]=v1.z;  xv[7]=v1.w;
    xv[8]=v2.x;  xv[9]=v2.y;  xv[10]=v2.z; xv[11]=v2.w;
    xv[12]=v3.x; xv[13]=v3.y; xv[14]=v3.z; xv[15]=v3.w;
    xv[16]=v4.x; xv[17]=v4.y; xv[18]=v4.z; xv[19]=v4.w;
    xv[20]=x20;
    float xl = confRow[lbl];               // L1-hot 4B re-read

    float mx = xv[0];
    #pragma unroll
    for (int c = 1; c < CCLS; c++) mx = fmaxf(mx, xv[c]);
    float h = mx * LOG2E;
    float sum = 0.f;
    #pragma unroll
    for (int c = 0; c < CCLS; c++)
        sum += __builtin_exp2f(__builtin_fmaf(xv[c], LOG2E, -h));
    float ce = (mx + __builtin_log2f(sum) * LN2) - xl;
    float pt = __builtin_exp2f(-ce * LOG2E);
    float om = 1.f - pt;
    acc += (double)(F_ALPHA * om * __builtin_sqrtf(om) * ce);

    if (pos) {
        cnt_pos += 1;
        float dw = d.z - d.x, dh = d.w - d.y;
        float dcx = d.x + dw * 0.5f, dcy = d.y + dh * 0.5f;
        float4 g = tb[idx];
        float gw = g.z - g.x, gh = g.w - g.y;
        float gcx = g.x + gw * 0.5f, gcy = g.y + gh * 0.5f;
        float rdw = __builtin_amdgcn_rcpf(dw + EPS8);
        float rdh = __builtin_amdgcn_rcpf(dh + EPS8);
        float ex = (gcx - dcx) * rdw;
        float ey = (gcy - dcy) * rdh;
        float ew = __builtin_log2f(gw * rdw + EPS8) * LN2;
        float eh = __builtin_log2f(gh * rdh + EPS8) * LN2;
        float tcx = ex * dw + dcx, tcy = ey * dh + dcy;
        float tw = __builtin_exp2f(ew * LOG2E) * dw;
        float th = __builtin_exp2f(eh * LOG2E) * dh;
        float t0 = tcx - tw * 0.5f, t1 = tcy - th * 0.5f;
        float t2 = tcx + tw * 0.5f, t3 = tcy + th * 0.5f;
        float4 l = *locpP;
        float pcx = l.x * dw + dcx, pcy = l.y * dh + dcy;
        float pw = __builtin_exp2f(l.z * LOG2E) * dw;
        float ph = __builtin_exp2f(l.w * LOG2E) * dh;
        float q0 = pcx - pw * 0.5f, q1 = pcy - ph * 0.5f;
        float q2 = pcx + pw * 0.5f, q3 = pcy + ph * 0.5f;
        float ix0 = fmaxf(q0, t0), iy0 = fmaxf(q1, t1);
        float ix1 = fminf(q2, t2), iy1 = fminf(q3, t3);
        float iw = fmaxf(ix1 - ix0, 0.f), ih = fmaxf(iy1 - iy0, 0.f);
        float inter = iw * ih;
        float pa = (q2 - q0) * (q3 - q1);
        float ta = (t2 - t0) * (t3 - t1);
        float uni = pa + ta - inter;
        float iou = inter * __builtin_amdgcn_rcpf(uni + EPS7);
        float e0 = fminf(q0, t0), e1 = fminf(q1, t1);
        float e2 = fmaxf(q2, t2), e3 = fmaxf(q3, t3);
        float ewd = fmaxf(e2 - e0, 0.f), ehd = fmaxf(e3 - e1, 0.f);
        float encl = ewd * ehd;
        float giou = iou - (encl - uni) * __builtin_amdgcn_rcpf(encl + EPS7);
        acc += (double)(1.f - giou);
    }
}

// ---------------------------------------------------------------------------
// Kernel B: fused bt + inverted force-match + focal + GIoU.
// 2 anchors per thread. Conf loads issued AFTER barrier 1 / BEFORE the bt
// loop: their ~600cyc latency hides under the bt scan; barrier 2's implicit
// vmcnt(0) lands after they're done. bt loop in R6 shape (unroll 4) for
// scalar-pipe GT loads.
// ---------------------------------------------------------------------------
__global__ __launch_bounds__(256, 4)
void loss_kernel(const float4* __restrict__ locp,
                 const float*  __restrict__ conf,
                 const float4* __restrict__ dbox,
                 const float4* __restrict__ gt,
                 const float*  __restrict__ garea,
                 const int*    __restrict__ gtl,
                 const unsigned* __restrict__ bp,
                 double* __restrict__ partS,
                 int*    __restrict__ partC,
                 int P, int M)
{
    __shared__ float4 tb[MAXM];
    __shared__ int    tl[MAXM];
    __shared__ int    ovr[512];            // force-match override: GT j or -1
    __shared__ double sv[4];
    __shared__ int    sc[4];

    const int t  = threadIdx.x;
    const int b  = blockIdx.y;
    const int p0 = blockIdx.x * 512;
    const int pA = p0 + t;
    const int pB = p0 + 256 + t;
    const bool validA = (pA < P);
    const bool validB = (pB < P);

    const float4 dA = dbox[validA ? pA : (P - 1)];
    const float4 dB = dbox[validB ? pB : (P - 1)];

    ovr[t] = -1; ovr[t + 256] = -1;
    if (t < M) {
        tb[t] = gt[(size_t)b * M + t];
        tl[t] = gtl[(size_t)b * M + t];
    }
    __syncthreads();                       // barrier 1: ovr/tb/tl visible

    // ---- issue conf loads NOW (after barrier 1, before bt loop) ----
    const size_t bP = (size_t)b * P;
    const float* rowA = conf + (bP + (validA ? pA : 0)) * CCLS;
    const float* rowB = conf + (bP + (validB ? pB : 0)) * CCLS;
    float4 a0 = ldg4u(rowA +  0), a1 = ldg4u(rowA +  4), a2 = ldg4u(rowA + 8),
           a3 = ldg4u(rowA + 12), a4 = ldg4u(rowA + 16);
    float  a20 = rowA[20];
    float4 c0 = ldg4u(rowB +  0), c1 = ldg4u(rowB +  4), c2 = ldg4u(rowB + 8),
           c3 = ldg4u(rowB + 12), c4 = ldg4u(rowB + 16);
    float  c20 = rowB[20];

    // inverted force-match: last-wins == max GT index wins
    if (t < M) {
        unsigned q = bp[(size_t)b * M + t] - (unsigned)p0;
        if (q < 512u) atomicMax(&ovr[q], t);
    }

    // bt for both anchors; GT via wave-uniform scalar loads, zero LDS.
    // Cross-mult compare: iou_m > iou_best <=> inter_m*bd > bi*den_m.
    const float daA = (dA.z - dA.x) * (dA.w - dA.y);
    const float daB = (dB.z - dB.x) * (dB.w - dB.y);
    const float4* gtb = gt + (size_t)b * M;
    const float*  gab = garea + (size_t)b * M;
    float biA = -1.f, bdA = 1.f, biB = -1.f, bdB = 1.f;
    int   bmA = 0, bmB = 0;
    #pragma unroll 4
    for (int m = 0; m < M; m++) {
        float4 g = gtb[m];
        float ta = gab[m];
        {
            float lx = fmaxf(dA.x, g.x), ly = fmaxf(dA.y, g.y);
            float rx = fminf(dA.z, g.z), ry = fminf(dA.w, g.w);
            float iw = fmaxf(rx - lx, 0.f), ih = fmaxf(ry - ly, 0.f);
            float inter = iw * ih;
            float den = daA + ta - inter;
            if (inter * bdA > biA * den) { biA = inter; bdA = den; bmA = m; }
        }
        {
            float lx = fmaxf(dB.x, g.x), ly = fmaxf(dB.y, g.y);
            float rx = fminf(dB.z, g.z), ry = fminf(dB.w, g.w);
            float iw = fmaxf(rx - lx, 0.f), ih = fmaxf(ry - ly, 0.f);
            float inter = iw * ih;
            float den = daB + ta - inter;
            if (inter * bdB > biB * den) { biB = inter; bdB = den; bmB = m; }
        }
    }
    __syncthreads();                       // barrier 2: ovr + conf loads done

    double acc = 0.0;
    int cnt_pos = 0;
    anchor_loss(validA, dA, biA, bdA, bmA, ovr[t], tl, tb,
                a0, a1, a2, a3, a4, a20,
                rowA, locp + bP + (validA ? pA : 0), acc, cnt_pos);
    anchor_loss(validB, dB, biB, bdB, bmB, ovr[t + 256], tl, tb,
                c0, c1, c2, c3, c4, c20,
                rowB, locp + bP + (validB ? pB : 0), acc, cnt_pos);

    for (int o = 32; o > 0; o >>= 1) {
        acc += __shfl_down(acc, o, 64);
        cnt_pos += __shfl_down(cnt_pos, o, 64);
    }
    int w = t >> 6, lane = t & 63;
    if (lane == 0) { sv[w] = acc; sc[w] = cnt_pos; }
    __syncthreads();
    if (t == 0) {
        int slot = blockIdx.y * gridDim.x + blockIdx.x;
        partS[slot] = sv[0] + sv[1] + sv[2] + sv[3];
        partC[slot] = sc[0] + sc[1] + sc[2] + sc[3];
    }
}

// ---------------------------------------------------------------------------
// Kernel C: reduce per-block partials, divide, write scalar output.
// ---------------------------------------------------------------------------
__global__ __launch_bounds__(256)
void final_kernel(const double* __restrict__ partS,
                  const int*    __restrict__ partC,
                  float* __restrict__ out, int n)
{
    __shared__ double sv[4];
    __shared__ long long sc[4];
    const int t = threadIdx.x;
    double a = 0.0; long long c = 0;
    for (int i = t; i < n; i += 256) { a += partS[i]; c += partC[i]; }
    for (int o = 32; o > 0; o >>= 1) {
        a += __shfl_down(a, o, 64);
        c += __shfl_down(c, o, 64);
    }
    int w = t >> 6, lane = t & 63;
    if (lane == 0) { sv[w] = a; sc[w] = c; }
    __syncthreads();
    if (t == 0) {
        double s = sv[0] + sv[1] + sv[2] + sv[3];
        long long np = sc[0] + sc[1] + sc[2] + sc[3];
        out[0] = (np == 0) ? 0.0f : (float)(s / (double)np);
    }
}

// ---------------------------------------------------------------------------
extern "C" void kernel_launch(void* const* d_in, const int* in_sizes, int n_in,
                              void* d_out, int out_size, void* d_ws, size_t ws_size,
                              hipStream_t stream)
{
    const float* locp = (const float*)d_in[0];   // [B,P,4]
    const float* conf = (const float*)d_in[1];   // [B,P,C]
    const float* dbox = (const float*)d_in[2];   // [P,4]
    const float* gt   = (const float*)d_in[3];   // [B,M,4]
    const int*   gtl  = (const int*)d_in[4];     // [B,M]

    const int P  = in_sizes[2] / 4;
    const long long BP = (long long)in_sizes[0] / 4;
    const int B  = (int)(BP / P);
    const int M  = in_sizes[4] / B;

    const int nblk = (P + 511) / 512;
    const int nPart = nblk * B;

    // ws layout: bp[B*M] u32 | garea[B*M] f32 | partS[nPart] f64 | partC i32
    char* ws = (char*)d_ws;
    unsigned* bp = (unsigned*)ws;
    size_t off = ((size_t)B * M * 4 + 15) & ~(size_t)15;
    float* garea = (float*)(ws + off);
    off += ((size_t)B * M * 4 + 15) & ~(size_t)15;
    double* partS = (double*)(ws + off);
    off += (size_t)nPart * 8;
    int* partC = (int*)(ws + off);

    dim3 gridBP((M + GGRP - 1) / GGRP, B);
    dim3 grid(nblk, B);
    bp_kernel<<<gridBP, 256, 0, stream>>>((const float4*)dbox, (const float4*)gt,
                                          bp, garea, P, M);
    loss_kernel<<<grid, 256, 0, stream>>>((const float4*)locp, conf,
                                          (const float4*)dbox, (const float4*)gt,
                                          garea, gtl, bp, partS, partC, P, M);
    final_kernel<<<1, 256, 0, stream>>>(partS, partC, (float*)d_out, nPart);
}

// Round 9
// 284.161 us; speedup vs baseline: 1.1280x; 1.0054x over previous
//
#include <hip/hip_runtime.h>
#include <cstdint>
#include <cstddef>

#define F_ALPHA 0.5f
#define THRESH  0.5f
#define EPS8    1e-8f
#define EPS7    1e-7f
#define MAXM    64
#define CCLS    21
#define GGRP    4      // GTs per bp block
#define LOG2E   1.4426950408889634f
#define LN2     0.6931471805599453f

// unaligned 16B global load (conf rows are 84B-strided, only 4B-aligned)
__device__ __forceinline__ float4 ldg4u(const float* p) {
    float4 v;
    __builtin_memcpy(&v, p, 16);
    return v;
}

// ---------------------------------------------------------------------------
// Kernel A: per-GT best prior (bp). One block owns GGRP GTs of one image.
// Register-local running (inter,den) max via cross-mult compare (no per-IoU
// trans op); ONE cross-lane reduction at the end. Also emits garea.
// grid = (ceil(M/GGRP), B), block = 256.
// ---------------------------------------------------------------------------
__global__ __launch_bounds__(256)
void bp_kernel(const float4* __restrict__ dbox,
               const float4* __restrict__ gt,
               unsigned* __restrict__ bp,
               float* __restrict__ garea,
               int P, int M)
{
    __shared__ unsigned long long wkey[GGRP][4];

    const int b  = blockIdx.y;
    const int m0 = blockIdx.x * GGRP;
    const int t  = threadIdx.x;
    const int w  = t >> 6, lane = t & 63;

    float4 gb[GGRP]; float ga[GGRP];
    #pragma unroll
    for (int g = 0; g < GGRP; g++) {
        int m = min(m0 + g, M - 1);           // pad entries discarded later
        float4 gg = gt[(size_t)b * M + m];
        gb[g] = gg;
        ga[g] = (gg.z - gg.x) * (gg.w - gg.y);
    }

    // running best as (inter, den) pair: iou_a > iou_b <=> ia*db > ib*da
    float    bi[GGRP], bd[GGRP];
    unsigned bestp[GGRP];
    #pragma unroll
    for (int g = 0; g < GGRP; g++) { bi[g] = 0.f; bd[g] = 1.f; bestp[g] = 0u; }

    for (int p = t; p < P; p += 256) {
        float4 d = dbox[p];
        float darea = (d.z - d.x) * (d.w - d.y);
        #pragma unroll
        for (int g = 0; g < GGRP; g++) {
            float4 gg = gb[g];
            float lx = fmaxf(d.x, gg.x), ly = fmaxf(d.y, gg.y);
            float rx = fminf(d.z, gg.z), ry = fminf(d.w, gg.w);
            float iw = fmaxf(rx - lx, 0.f), ih = fmaxf(ry - ly, 0.f);
            float inter = iw * ih;
            float den = darea + ga[g] - inter;
            // strict > : within-thread ties keep lowest p (p increases)
            if (inter * bd[g] > bi[g] * den) {
                bi[g] = inter; bd[g] = den; bestp[g] = (unsigned)p;
            }
        }
    }

    // one-time reduction: key = iou_bits<<32 | ~p  (max => max iou, min p)
    #pragma unroll
    for (int g = 0; g < GGRP; g++) {
        float iou = bi[g] * __builtin_amdgcn_rcpf(bd[g]);   // 0 when bi==0
        unsigned long long k =
            ((unsigned long long)__float_as_uint(iou) << 32)
            | (unsigned long long)(0xFFFFFFFFu - bestp[g]);
        #pragma unroll
        for (int o = 1; o < 64; o <<= 1) {
            unsigned long long k2 = __shfl_xor(k, o, 64);
            if (k2 > k) k = k2;
        }
        if (lane == 0) wkey[g][w] = k;
    }
    __syncthreads();
    if (t < GGRP) {
        unsigned long long k0 = wkey[t][0], k1 = wkey[t][1];
        unsigned long long k2 = wkey[t][2], k3 = wkey[t][3];
        unsigned long long ka = (k0 > k1) ? k0 : k1;
        unsigned long long kb = (k2 > k3) ? k2 : k3;
        unsigned long long k  = (ka > kb) ? ka : kb;
        int m = m0 + t;
        if (m < M) {
            bp[(size_t)b * M + m] = 0xFFFFFFFFu - (unsigned)(k & 0xFFFFFFFFull);
            float4 gg = gt[(size_t)b * M + m];
            garea[(size_t)b * M + m] = (gg.z - gg.x) * (gg.w - gg.y);
        }
        // all-zero row: key stays (0, ~0) -> p = 0, matching argmax fallback
    }
}

// ---------------------------------------------------------------------------
// focal + GIoU for one anchor, conf row already in registers (loaded BEFORE
// the bt loop -> latency hidden). x[lbl] via register cndmask-select under
// the rare `pos` mask (negatives use xv[0] free) — no dependent global load
// in the epilogue.
// ---------------------------------------------------------------------------
__device__ __forceinline__ void anchor_loss(
    bool valid, float4 d, float bi, float bd, int bm, int ov,
    const int* __restrict__ tl, const float4* __restrict__ tb,
    float4 v0, float4 v1, float4 v2, float4 v3, float4 v4, float x20,
    const float4* locpP,
    double& acc, int& cnt_pos)
{
    if (!valid) return;

    int  idx = bm;
    bool pos = (bi >= THRESH * bd);        // iou >= 0.5
    if (ov >= 0) { idx = ov; pos = true; }

    float xv[CCLS];
    xv[0]=v0.x;  xv[1]=v0.y;  xv[2]=v0.z;  xv[3]=v0.w;
    xv[4]=v1.x;  xv[5]=v1.y;  xv[6]=v1.z;  xv[7]=v1.w;
    xv[8]=v2.x;  xv[9]=v2.y;  xv[10]=v2.z; xv[11]=v2.w;
    xv[12]=v3.x; xv[13]=v3.y; xv[14]=v3.z; xv[15]=v3.w;
    xv[16]=v4.x; xv[17]=v4.y; xv[18]=v4.z; xv[19]=v4.w;
    xv[20]=x20;

    // xl = xv[lbl]; lbl==0 for negatives, register select for rare positives
    float xl = xv[0];
    if (pos) {
        int lbl = tl[idx];
        #pragma unroll
        for (int c = 1; c < CCLS; c++) xl = (lbl == c) ? xv[c] : xl;
    }

    float mx = xv[0];
    #pragma unroll
    for (int c = 1; c < CCLS; c++) mx = fmaxf(mx, xv[c]);
    float h = mx * LOG2E;
    float sum = 0.f;
    #pragma unroll
    for (int c = 0; c < CCLS; c++)
        sum += __builtin_exp2f(__builtin_fmaf(xv[c], LOG2E, -h));
    float ce = (mx + __builtin_log2f(sum) * LN2) - xl;
    float pt = __builtin_exp2f(-ce * LOG2E);
    float om = 1.f - pt;
    acc += (double)(F_ALPHA * om * __builtin_sqrtf(om) * ce);

    if (pos) {
        cnt_pos += 1;
        float dw = d.z - d.x, dh = d.w - d.y;
        float dcx = d.x + dw * 0.5f, dcy = d.y + dh * 0.5f;
        float4 g = tb[idx];
        float gw = g.z - g.x, gh = g.w - g.y;
        float gcx = g.x + gw * 0.5f, gcy = g.y + gh * 0.5f;
        float rdw = __builtin_amdgcn_rcpf(dw + EPS8);
        float rdh = __builtin_amdgcn_rcpf(dh + EPS8);
        float ex = (gcx - dcx) * rdw;
        float ey = (gcy - dcy) * rdh;
        float ew = __builtin_log2f(gw * rdw + EPS8) * LN2;
        float eh = __builtin_log2f(gh * rdh + EPS8) * LN2;
        float tcx = ex * dw + dcx, tcy = ey * dh + dcy;
        float tw = __builtin_exp2f(ew * LOG2E) * dw;
        float th = __builtin_exp2f(eh * LOG2E) * dh;
        float t0 = tcx - tw * 0.5f, t1 = tcy - th * 0.5f;
        float t2 = tcx + tw * 0.5f, t3 = tcy + th * 0.5f;
        float4 l = *locpP;
        float pcx = l.x * dw + dcx, pcy = l.y * dh + dcy;
        float pw = __builtin_exp2f(l.z * LOG2E) * dw;
        float ph = __builtin_exp2f(l.w * LOG2E) * dh;
        float q0 = pcx - pw * 0.5f, q1 = pcy - ph * 0.5f;
        float q2 = pcx + pw * 0.5f, q3 = pcy + ph * 0.5f;
        float ix0 = fmaxf(q0, t0), iy0 = fmaxf(q1, t1);
        float ix1 = fminf(q2, t2), iy1 = fminf(q3, t3);
        float iw = fmaxf(ix1 - ix0, 0.f), ih = fmaxf(iy1 - iy0, 0.f);
        float inter = iw * ih;
        float pa = (q2 - q0) * (q3 - q1);
        float ta = (t2 - t0) * (t3 - t1);
        float uni = pa + ta - inter;
        float iou = inter * __builtin_amdgcn_rcpf(uni + EPS7);
        float e0 = fminf(q0, t0), e1 = fminf(q1, t1);
        float e2 = fmaxf(q2, t2), e3 = fmaxf(q3, t3);
        float ewd = fmaxf(e2 - e0, 0.f), ehd = fmaxf(e3 - e1, 0.f);
        float encl = ewd * ehd;
        float giou = iou - (encl - uni) * __builtin_amdgcn_rcpf(encl + EPS7);
        acc += (double)(1.f - giou);
    }
}

// ---------------------------------------------------------------------------
// Kernel B: fused bt + inverted force-match + focal + GIoU.
// 2 anchors per thread. Conf loads issued AFTER barrier 1 / BEFORE the bt
// loop (latency hidden under the bt scan; barrier 2's implicit vmcnt(0)
// lands after they're done). bt loop unroll 4 for scalar-pipe GT loads.
// ---------------------------------------------------------------------------
__global__ __launch_bounds__(256, 4)
void loss_kernel(const float4* __restrict__ locp,
                 const float*  __restrict__ conf,
                 const float4* __restrict__ dbox,
                 const float4* __restrict__ gt,
                 const float*  __restrict__ garea,
                 const int*    __restrict__ gtl,
                 const unsigned* __restrict__ bp,
                 double* __restrict__ partS,
                 int*    __restrict__ partC,
                 int P, int M)
{
    __shared__ float4 tb[MAXM];
    __shared__ int    tl[MAXM];
    __shared__ int    ovr[512];            // force-match override: GT j or -1
    __shared__ double sv[4];
    __shared__ int    sc[4];

    const int t  = threadIdx.x;
    const int b  = blockIdx.y;
    const int p0 = blockIdx.x * 512;
    const int pA = p0 + t;
    const int pB = p0 + 256 + t;
    const bool validA = (pA < P);
    const bool validB = (pB < P);

    const float4 dA = dbox[validA ? pA : (P - 1)];
    const float4 dB = dbox[validB ? pB : (P - 1)];

    ovr[t] = -1; ovr[t + 256] = -1;
    if (t < M) {
        tb[t] = gt[(size_t)b * M + t];
        tl[t] = gtl[(size_t)b * M + t];
    }
    __syncthreads();                       // barrier 1: ovr/tb/tl visible

    // ---- issue conf loads NOW (after barrier 1, before bt loop) ----
    const size_t bP = (size_t)b * P;
    const float* rowA = conf + (bP + (validA ? pA : 0)) * CCLS;
    const float* rowB = conf + (bP + (validB ? pB : 0)) * CCLS;
    float4 a0 = ldg4u(rowA +  0), a1 = ldg4u(rowA +  4), a2 = ldg4u(rowA + 8),
           a3 = ldg4u(rowA + 12), a4 = ldg4u(rowA + 16);
    float  a20 = rowA[20];
    float4 c0 = ldg4u(rowB +  0), c1 = ldg4u(rowB +  4), c2 = ldg4u(rowB + 8),
           c3 = ldg4u(rowB + 12), c4 = ldg4u(rowB + 16);
    float  c20 = rowB[20];

    // inverted force-match: last-wins == max GT index wins
    if (t < M) {
        unsigned q = bp[(size_t)b * M + t] - (unsigned)p0;
        if (q < 512u) atomicMax(&ovr[q], t);
    }

    // bt for both anchors; GT via wave-uniform scalar loads, zero LDS.
    // Cross-mult compare: iou_m > iou_best <=> inter_m*bd > bi*den_m.
    const float daA = (dA.z - dA.x) * (dA.w - dA.y);
    const float daB = (dB.z - dB.x) * (dB.w - dB.y);
    const float4* gtb = gt + (size_t)b * M;
    const float*  gab = garea + (size_t)b * M;
    float biA = -1.f, bdA = 1.f, biB = -1.f, bdB = 1.f;
    int   bmA = 0, bmB = 0;
    #pragma unroll 4
    for (int m = 0; m < M; m++) {
        float4 g = gtb[m];
        float ta = gab[m];
        {
            float lx = fmaxf(dA.x, g.x), ly = fmaxf(dA.y, g.y);
            float rx = fminf(dA.z, g.z), ry = fminf(dA.w, g.w);
            float iw = fmaxf(rx - lx, 0.f), ih = fmaxf(ry - ly, 0.f);
            float inter = iw * ih;
            float den = daA + ta - inter;
            if (inter * bdA > biA * den) { biA = inter; bdA = den; bmA = m; }
        }
        {
            float lx = fmaxf(dB.x, g.x), ly = fmaxf(dB.y, g.y);
            float rx = fminf(dB.z, g.z), ry = fminf(dB.w, g.w);
            float iw = fmaxf(rx - lx, 0.f), ih = fmaxf(ry - ly, 0.f);
            float inter = iw * ih;
            float den = daB + ta - inter;
            if (inter * bdB > biB * den) { biB = inter; bdB = den; bmB = m; }
        }
    }
    __syncthreads();                       // barrier 2: ovr + conf loads done

    double acc = 0.0;
    int cnt_pos = 0;
    anchor_loss(validA, dA, biA, bdA, bmA, ovr[t], tl, tb,
                a0, a1, a2, a3, a4, a20,
                locp + bP + (validA ? pA : 0), acc, cnt_pos);
    anchor_loss(validB, dB, biB, bdB, bmB, ovr[t + 256], tl, tb,
                c0, c1, c2, c3, c4, c20,
                locp + bP + (validB ? pB : 0), acc, cnt_pos);

    for (int o = 32; o > 0; o >>= 1) {
        acc += __shfl_down(acc, o, 64);
        cnt_pos += __shfl_down(cnt_pos, o, 64);
    }
    int w = t >> 6, lane = t & 63;
    if (lane == 0) { sv[w] = acc; sc[w] = cnt_pos; }
    __syncthreads();
    if (t == 0) {
        int slot = blockIdx.y * gridDim.x + blockIdx.x;
        partS[slot] = sv[0] + sv[1] + sv[2] + sv[3];
        partC[slot] = sc[0] + sc[1] + sc[2] + sc[3];
    }
}

// ---------------------------------------------------------------------------
// Kernel C: reduce per-block partials, divide, write scalar output.
// ---------------------------------------------------------------------------
__global__ __launch_bounds__(256)
void final_kernel(const double* __restrict__ partS,
                  const int*    __restrict__ partC,
                  float* __restrict__ out, int n)
{
    __shared__ double sv[4];
    __shared__ long long sc[4];
    const int t = threadIdx.x;
    double a = 0.0; long long c = 0;
    for (int i = t; i < n; i += 256) { a += partS[i]; c += partC[i]; }
    for (int o = 32; o > 0; o >>= 1) {
        a += __shfl_down(a, o, 64);
        c += __shfl_down(c, o, 64);
    }
    int w = t >> 6, lane = t & 63;
    if (lane == 0) { sv[w] = a; sc[w] = c; }
    __syncthreads();
    if (t == 0) {
        double s = sv[0] + sv[1] + sv[2] + sv[3];
        long long np = sc[0] + sc[1] + sc[2] + sc[3];
        out[0] = (np == 0) ? 0.0f : (float)(s / (double)np);
    }
}

// ---------------------------------------------------------------------------
extern "C" void kernel_launch(void* const* d_in, const int* in_sizes, int n_in,
                              void* d_out, int out_size, void* d_ws, size_t ws_size,
                              hipStream_t stream)
{
    const float* locp = (const float*)d_in[0];   // [B,P,4]
    const float* conf = (const float*)d_in[1];   // [B,P,C]
    const float* dbox = (const float*)d_in[2];   // [P,4]
    const float* gt   = (const float*)d_in[3];   // [B,M,4]
    const int*   gtl  = (const int*)d_in[4];     // [B,M]

    const int P  = in_sizes[2] / 4;
    const long long BP = (long long)in_sizes[0] / 4;
    const int B  = (int)(BP / P);
    const int M  = in_sizes[4] / B;

    const int nblk = (P + 511) / 512;
    const int nPart = nblk * B;

    // ws layout: bp[B*M] u32 | garea[B*M] f32 | partS[nPart] f64 | partC i32
    char* ws = (char*)d_ws;
    unsigned* bp = (unsigned*)ws;
    size_t off = ((size_t)B * M * 4 + 15) & ~(size_t)15;
    float* garea = (float*)(ws + off);
    off += ((size_t)B * M * 4 + 15) & ~(size_t)15;
    double* partS = (double*)(ws + off);
    off += (size_t)nPart * 8;
    int* partC = (int*)(ws + off);

    dim3 gridBP((M + GGRP - 1) / GGRP, B);
    dim3 grid(nblk, B);
    bp_kernel<<<gridBP, 256, 0, stream>>>((const float4*)dbox, (const float4*)gt,
                                          bp, garea, P, M);
    loss_kernel<<<grid, 256, 0, stream>>>((const float4*)locp, conf,
                                          (const float4*)dbox, (const float4*)gt,
                                          garea, gtl, bp, partS, partC, P, M);
    final_kernel<<<1, 256, 0, stream>>>(partS, partC, (float*)d_out, nPart);
}